// Round 8
// baseline (1838.257 us; speedup 1.0000x reference)
//
#include <hip/hip_runtime.h>
#include <hip/hip_bf16.h>

#define B_    16
#define CIN   64
#define Hn    64
#define Wn    64
#define HID   128

// ---- dynamic LDS arena (bytes) ----
// sAx : [512 co][256B] bf16 x-weights, 16B slots XOR-swizzled by (co&15)
// sH  : 66 rows x 272B  (row r = h_prev[w=r-1]; rows 0,65 zero guards)
// sX  : 65 rows x 144B  (row r = x[w=r-1]; row 0 zero guard)
// sB  : 512 f32 combined bias b_is+b_ss
#define AX_OFF    0
#define AX_BYTES  (512 * 256)
#define SH_OFF    AX_BYTES
#define SHS_B     272
#define SH_BYTES  (66 * SHS_B)
#define SX_OFF    (SH_OFF + SH_BYTES)
#define SXS_B     144
#define SX_BYTES  (65 * SXS_B)
#define BIAS_OFF  (SX_OFF + SX_BYTES)
#define LDS_TOTAL (BIAS_OFF + 512 * 4)     // 160432 <= 163840

typedef __attribute__((ext_vector_type(8))) short bfrag_t;   // 8 bf16 (4 VGPRs)
typedef __attribute__((ext_vector_type(4))) float f4_t;

static __device__ __forceinline__ short f2bf(float f) {
    union { __hip_bfloat16 h; short s; } u;
    u.h = __float2bfloat16(f);
    return u.s;
}
static __device__ __forceinline__ float sigm(float z)  { return 1.f / (1.f + __expf(-z)); }
static __device__ __forceinline__ float tanhf_(float z){ return 2.f / (1.f + __expf(-2.f * z)) - 1.f; }

static __device__ __forceinline__ unsigned long long pack4bf(const float* hv) {
    unsigned p0 = (unsigned)(unsigned short)f2bf(hv[0]) |
                  ((unsigned)(unsigned short)f2bf(hv[1]) << 16);
    unsigned p1 = (unsigned)(unsigned short)f2bf(hv[2]) |
                  ((unsigned)(unsigned short)f2bf(hv[3]) << 16);
    return (unsigned long long)p0 | ((unsigned long long)p1 << 32);
}

// lgkm-only barrier: never drains vmcnt (out-stores / x-prefetch stay in flight).
#define BAR_LGKM() do { \
    asm volatile("s_waitcnt lgkmcnt(0)" ::: "memory"); \
    __builtin_amdgcn_s_barrier(); \
    __builtin_amdgcn_sched_barrier(0); \
} while (0)

#define MFMA(a, b, c) __builtin_amdgcn_mfma_f32_16x16x32_bf16((a), (b), (c), 0, 0, 0)

// B-fragment reads (R1-proven shifted-panel addressing, byte offsets)
#define READ_BX(NT, KTX) \
    (*(const bfrag_t*)(smem + SX_OFF + ((NT) * 16 + l15 + ((KTX) >> 1)) * SXS_B + \
                       ((KTX) & 1) * 64 + quad * 16))
#define READ_BH(NT, KTH) \
    (*(const bfrag_t*)(smem + SH_OFF + ((NT) * 16 + l15 + ((KTH) >> 2)) * SHS_B + \
                       ((KTH) & 3) * 64 + quad * 16))
// A_x fragment: row co, slot (ktx*4+quad) XOR-swizzled by l15 (co&15 == l15)
#define READ_AX(G, KTX) \
    (*(const bfrag_t*)(smem + AX_OFF + ((G) * HID + 16 * wv + l15) * 256 + \
                       ((((KTX) * 4 + quad) * 16) ^ (l15 << 4))))
#define BIAS4(G) \
    (*(const f4_t*)(smem + BIAS_OFF + ((G) * HID + 16 * wv + quad * 4) * 4))

// x-GEMM for an nt-pair: acc init from bias, K=128 (4 ktx), A_x from LDS read once
#define XPASS(Aarr, NT0) do { \
    _Pragma("unroll") \
    for (int g = 0; g < 4; ++g) { \
        const f4_t bi = BIAS4(g); \
        Aarr[g][0] = bi; Aarr[g][1] = bi; \
    } \
    _Pragma("unroll") \
    for (int ktx = 0; ktx < 4; ++ktx) { \
        const bfrag_t bx0 = READ_BX((NT0),     ktx); \
        const bfrag_t bx1 = READ_BX((NT0) + 1, ktx); \
        _Pragma("unroll") \
        for (int g = 0; g < 4; ++g) { \
            const bfrag_t ax = READ_AX(g, ktx); \
            Aarr[g][0] = MFMA(ax, bx0, Aarr[g][0]); \
            Aarr[g][1] = MFMA(ax, bx1, Aarr[g][1]); \
        } \
    } \
} while (0)

// h-GEMM (K=384) + lane-local phase C for one 16-w column block NT
#define HPASS_C(Aarr, NP, NT, PKOUT) do { \
    f4_t ac0 = Aarr[0][NP], ac1 = Aarr[1][NP], ac2 = Aarr[2][NP], ac3 = Aarr[3][NP]; \
    _Pragma("unroll") \
    for (int kth = 0; kth < 12; ++kth) { \
        const bfrag_t bh = READ_BH(NT, kth); \
        ac0 = MFMA(a_h[0][kth], bh, ac0); \
        ac1 = MFMA(a_h[1][kth], bh, ac1); \
        ac2 = MFMA(a_h[2][kth], bh, ac2); \
        ac3 = MFMA(a_h[3][kth], bh, ac3); \
    } \
    float hv[4]; \
    _Pragma("unroll") \
    for (int r = 0; r < 4; ++r) { \
        const float ig = sigm(ac0[r]); \
        const float fg = sigm(ac1[r]); \
        const float og = sigm(ac2[r]); \
        const float gg = tanhf_(ac3[r]); \
        const float c  = fg * creg[NT][r] + ig * gg; \
        creg[NT][r] = c; \
        hv[r] = og * tanhf_(c); \
        out[((b * HID + 16 * wv + quad * 4 + r) * Hn + h) * Wn + (NT) * 16 + l15] = hv[r]; \
    } \
    PKOUT = pack4bf(hv); \
} while (0)

// deferred h write (one phase after its readers have passed the barrier)
#define WRITE_H(K, PK) \
    *(unsigned long long*)(smem + SH_OFF + (16 * (K) + l15 + 1) * SHS_B + \
                           (16 * wv + quad * 4) * 2) = (PK)

extern "C" __global__ __launch_bounds__(512, 2)
void rowlstm_kernel(const float* __restrict__ x,
                    const float* __restrict__ w_is,
                    const float* __restrict__ b_is,
                    const float* __restrict__ w_ss,
                    const float* __restrict__ b_ss,
                    float* __restrict__ out,
                    unsigned char* __restrict__ ws)
{
    extern __shared__ char smem[];
    const int tid  = threadIdx.x;
    const int b    = blockIdx.x;          // one block = one batch; no cross-block deps at all
    const int lane = tid & 63;
    const int wv   = tid >> 6;            // 8 waves; wave wv owns channels [16wv,16wv+16)
    const int l15  = lane & 15;
    const int quad = lane >> 4;
    (void)ws;

    // ---- A_h (w_ss) fragments in registers: 4 gates x 12 kth = 192 VGPR ----
    // K layout (h part, 384): [0,128) tap0 | [128,256) tap1 | [256,384) tap2
    bfrag_t a_h[4][12];
    #pragma unroll
    for (int g = 0; g < 4; ++g) {
        const int co = g * HID + 16 * wv + l15;
        #pragma unroll
        for (int kth = 0; kth < 12; ++kth) {
            const int tap = kth >> 2, cb = kth & 3;
            const float* p = &w_ss[(co * HID + cb * 32 + quad * 8) * 3 + tap];
            bfrag_t v;
            #pragma unroll
            for (int j = 0; j < 8; ++j) v[j] = f2bf(p[j * 3]);
            a_h[g][kth] = v;
        }
    }

    // ---- sAx fill: thread fills row co = tid (16 slots of 16B, XOR-swizzled) ----
    {
        const int m = tid;
        #pragma unroll
        for (int k16 = 0; k16 < 16; ++k16) {
            bfrag_t v;
            #pragma unroll
            for (int j = 0; j < 8; ++j) {
                const int kk = k16 * 8 + j;     // [0,64) kw0 | [64,128) kw1
                const float val = (kk < 64) ? w_is[(m * CIN + kk) * 3 + 0]
                                            : w_is[(m * CIN + kk - 64) * 3 + 1];
                v[j] = f2bf(val);
            }
            *(bfrag_t*)(smem + AX_OFF + m * 256 + ((k16 * 16) ^ ((m & 15) << 4))) = v;
        }
    }

    // ---- combined bias (f32, exact) ----
    *(float*)(smem + BIAS_OFF + tid * 4) = b_is[tid] + b_ss[tid];

    // ---- zero sH (incl. both guards; h_prev(row0)=0) and sX guard row 0 ----
    {
        bfrag_t z8 = {0,0,0,0,0,0,0,0};
        for (int s = tid; s < SH_BYTES / 16; s += 512)
            *(bfrag_t*)(smem + SH_OFF + s * 16) = z8;
        if (tid < SXS_B / 16)
            *(bfrag_t*)(smem + SX_OFF + tid * 16) = z8;
    }

    // ---- x staging: thread (xw, xcg) holds x[ci=8xcg..+7][xw]; build row 0, prefetch row 1 ----
    const int xw = tid & 63, xcg = tid >> 6;
    float xr[8];
    #pragma unroll
    for (int j = 0; j < 8; ++j)
        xr[j] = x[((b * CIN + xcg * 8 + j) * Hn + 0) * Wn + xw];
    {
        bfrag_t v;
        #pragma unroll
        for (int j = 0; j < 8; ++j) v[j] = f2bf(xr[j]);
        *(bfrag_t*)(smem + SX_OFF + (xw + 1) * SXS_B + xcg * 16) = v;
    }
    #pragma unroll
    for (int j = 0; j < 8; ++j)
        xr[j] = x[((b * CIN + xcg * 8 + j) * Hn + 1) * Wn + xw];

    float creg[4][4] = {{0.f}};
    __syncthreads();

    for (int h = 0; h < Hn; ++h) {
        unsigned long long pk0, pk1, pk2, pk3;

        // ---- column blocks 0,1: x-GEMM pair, then h-GEMM + gates per block ----
        f4_t A01[4][2];
        XPASS(A01, 0);
        HPASS_C(A01, 0, 0, pk0);
        HPASS_C(A01, 1, 1, pk1);
        BAR_LGKM();                 // (1) readers of sH rows 1..16 done -> W0 safe
        WRITE_H(0, pk0);

        // ---- column blocks 2,3 ----
        f4_t A23[4][2];
        XPASS(A23, 2);
        HPASS_C(A23, 0, 2, pk2);
        BAR_LGKM();                 // (2) readers of rows 17..32 done -> W1 safe
        WRITE_H(1, pk1);

        // mid-row x prefetch for row h+1 (off the register-pressure peak; ~1500cy to cover)
        {
            const int hp = (h + 1 < Hn) ? h + 1 : Hn - 1;
            #pragma unroll
            for (int j = 0; j < 8; ++j)
                xr[j] = x[((b * CIN + xcg * 8 + j) * Hn + hp) * Wn + xw];
        }

        HPASS_C(A23, 1, 3, pk3);
        BAR_LGKM();                 // (3) all sH readers of this row done -> W2/W3 safe
        WRITE_H(2, pk2);
        WRITE_H(3, pk3);

        // ---- tail: rebuild x panel for row h+1 (sX readers finished before BAR(2)) ----
        {
            bfrag_t v;
            #pragma unroll
            for (int j = 0; j < 8; ++j) v[j] = f2bf(xr[j]);
            *(bfrag_t*)(smem + SX_OFF + (xw + 1) * SXS_B + xcg * 16) = v;
        }
        BAR_LGKM();                 // (4) sH(new)+sX(new) visible -> next row
    }
}

extern "C" void kernel_launch(void* const* d_in, const int* in_sizes, int n_in,
                              void* d_out, int out_size, void* d_ws, size_t ws_size,
                              hipStream_t stream) {
    const float* x    = (const float*)d_in[0];
    const float* w_is = (const float*)d_in[1];
    const float* b_is = (const float*)d_in[2];
    const float* w_ss = (const float*)d_in[3];
    const float* b_ss = (const float*)d_in[4];
    float* out = (float*)d_out;
    unsigned char* ws = (unsigned char*)d_ws;

    // opt in to >64KB dynamic LDS (160432B total); idempotent, capture-safe host call
    hipFuncSetAttribute((const void*)rowlstm_kernel,
                        hipFuncAttributeMaxDynamicSharedMemorySize, LDS_TOTAL);

    // 16 blocks (one per batch), 512 threads, no inter-block communication.
    rowlstm_kernel<<<dim3(B_), dim3(512), LDS_TOTAL, stream>>>(x, w_is, b_is, w_ss, b_ss, out, ws);
}

// Round 9
// 391.143 us; speedup vs baseline: 4.6997x; 4.6997x over previous
//
#include <hip/hip_runtime.h>
#include <hip/hip_bf16.h>

#define B_    16
#define CIN   64
#define Hn    64
#define Wn    64
#define HID   128
#define SXS2  72    // sX2 row stride in shorts (144B, 16B-aligned)
#define SHS   136   // sH  row stride in shorts (272B, 16B-aligned)
#define NJC   8     // j-chunks per batch (16 channels each)
#define NGRID 256   // oversubscribed grid; 128 roles claimed by actual-XCD
#define POLL_TO 256 // L2 fast-spin budget per row (2 strikes -> permanent LLC)

typedef __attribute__((ext_vector_type(8))) short bfrag_t;   // 8 bf16 (4 VGPRs)
typedef __attribute__((ext_vector_type(4))) float f4_t;

// d_ws layout:
//   [0, 512KB)      : dataA [2][16][64][128] bf16 — L2-mode h bufs (plain store / sc0 load)
//   [512KB, 1MB)    : dataB — LLC h bufs (agent ops; fallback + LLC-mode)
//   [1MB, +4KB)     : per-b 256B flag line: words [0,32) = flagsA (L2), [32,64) = flagsB (LLC)
//   [1MB+4KB, +1KB) : claim state: [0..7] pool_cnt, [8] arrived, [9] over_cnt,
//                     [16+b] grp_cnt, [32+b*8+jc] grp_xcd+1
#define HBUF_SHORTS (B_ * Wn * HID)
#define HBUF_BYTES  (HBUF_SHORTS * 2)
#define DATA_A_OFF  0
#define DATA_B_OFF  (2 * HBUF_BYTES)
#define FLG_OFF     (4 * HBUF_BYTES)
#define CLAIM_OFF   (FLG_OFF + B_ * 256)

static __device__ __forceinline__ short f2bf(float f) {
    union { __hip_bfloat16 h; short s; } u;
    u.h = __float2bfloat16(f);
    return u.s;
}
static __device__ __forceinline__ float sigm(float z)  { return 1.f / (1.f + __expf(-z)); }
static __device__ __forceinline__ float tanhf_(float z){ return 2.f / (1.f + __expf(-2.f * z)) - 1.f; }

#define BAR_LGKM() do { \
    asm volatile("s_waitcnt lgkmcnt(0)" ::: "memory"); \
    __builtin_amdgcn_s_barrier(); \
    __builtin_amdgcn_sched_barrier(0); \
} while (0)

extern "C" __global__ __launch_bounds__(256, 1)
void rowlstm_kernel(const float* __restrict__ x,
                    const float* __restrict__ w_is,
                    const float* __restrict__ b_is,
                    const float* __restrict__ w_ss,
                    const float* __restrict__ b_ss,
                    float* __restrict__ out,
                    unsigned char* __restrict__ ws)
{
    const int tid  = threadIdx.x;
    const int lane = tid & 63;
    const int wv   = tid >> 6;
    const int l15  = lane & 15;
    const int quad = lane >> 4;

    // ---- XCD-aware role claim (tid0), broadcast via LDS ----
    __shared__ int sB, sJ, sM;
    if (tid == 0) {
        unsigned* cl = (unsigned*)(ws + CLAIM_OFF);
        unsigned xcd;
        asm volatile("s_getreg_b32 %0, hwreg(20, 0, 32)" : "=s"(xcd));  // HW_REG_XCC_ID [m09]
        xcd &= 7u;
        unsigned slot = __hip_atomic_fetch_add(&cl[xcd], 1u, __ATOMIC_RELAXED, __HIP_MEMORY_SCOPE_AGENT);
        int role = (slot < 16u) ? (int)(xcd * 16u + slot) : -1;
        __hip_atomic_fetch_add(&cl[8], 1u, __ATOMIC_RELEASE, __HIP_MEMORY_SCOPE_AGENT);
        if (role < 0) {   // overflow: wait for all native claims, then take a leftover role
            while (__hip_atomic_load(&cl[8], __ATOMIC_ACQUIRE, __HIP_MEMORY_SCOPE_AGENT) < (unsigned)NGRID)
                __builtin_amdgcn_s_sleep(8);
            unsigned ovr = __hip_atomic_fetch_add(&cl[9], 1u, __ATOMIC_RELAXED, __HIP_MEMORY_SCOPE_AGENT);
            unsigned base = 0;
            for (int k = 0; k < 8 && role < 0; ++k) {
                unsigned c = __hip_atomic_load(&cl[k], __ATOMIC_RELAXED, __HIP_MEMORY_SCOPE_AGENT);
                if (c > 16u) c = 16u;
                unsigned miss = 16u - c;
                if (ovr < base + miss) role = (int)(k * 16u + c + (ovr - base));
                base += miss;
            }
        }
        int bb = -1, jj = 0, mm = 0;
        if (role >= 0) {
            bb = (role >> 4) * 2 + ((role >> 3) & 1);   // xcd*2 + (slot>>3)
            jj = role & 7;
            __hip_atomic_store(&cl[32 + bb * 8 + jj], xcd + 1u, __ATOMIC_RELAXED, __HIP_MEMORY_SCOPE_AGENT);
            __hip_atomic_fetch_add(&cl[16 + bb], 1u, __ATOMIC_RELEASE, __HIP_MEMORY_SCOPE_AGENT);
            while (__hip_atomic_load(&cl[16 + bb], __ATOMIC_ACQUIRE, __HIP_MEMORY_SCOPE_AGENT) < 8u)
                __builtin_amdgcn_s_sleep(8);
            mm = 1;   // L2 mode iff all 8 members claimed from the same XCD
            for (int j = 0; j < 8; ++j)
                if (__hip_atomic_load(&cl[32 + bb * 8 + j], __ATOMIC_RELAXED, __HIP_MEMORY_SCOPE_AGENT) != xcd + 1u)
                    mm = 0;
        }
        sB = bb; sJ = jj; sM = mm;
    }
    __syncthreads();
    const int  b   = sB;
    const int  jc  = sJ;
    const bool l2m = (sM != 0);
    if (b < 0) return;   // surplus block

    short*    hbufA = (short*)(ws + DATA_A_OFF);
    short*    hbufB = (short*)(ws + DATA_B_OFF);
    unsigned* flgA  = (unsigned*)(ws + FLG_OFF + b * 256);
    unsigned* flgB  = flgA + 32;

    // LDS ~27 KB. Shifted-read panels (R1/R7-proven layout).
    __shared__ alignas(16) short sH[66 * SHS];
    __shared__ alignas(16) short sX2[65 * SXS2];

    // ---- A (weight) fragments, gate-major (R7 verbatim) ----
    bfrag_t a_frag[4][16];
    #pragma unroll
    for (int mt = 0; mt < 4; ++mt) {
        const int co = mt * HID + jc * 16 + l15;
        #pragma unroll
        for (int kt = 0; kt < 16; ++kt) {
            const int kk0 = kt * 32 + quad * 8;
            const float* p;
            if      (kt < 2)  p = &w_is[(co * CIN + kk0)         * 3 + 0];
            else if (kt < 4)  p = &w_is[(co * CIN + (kk0 - 64))  * 3 + 1];
            else if (kt < 8)  p = &w_ss[(co * HID + (kk0 - 128)) * 3 + 0];
            else if (kt < 12) p = &w_ss[(co * HID + (kk0 - 256)) * 3 + 1];
            else              p = &w_ss[(co * HID + (kk0 - 384)) * 3 + 2];
            bfrag_t v;
            #pragma unroll
            for (int j = 0; j < 8; ++j) v[j] = f2bf(p[j * 3]);
            a_frag[mt][kt] = v;
        }
    }

    float bias[4][4];
    #pragma unroll
    for (int g = 0; g < 4; ++g) {
        #pragma unroll
        for (int r = 0; r < 4; ++r) {
            const int co = g * HID + jc * 16 + quad * 4 + r;
            bias[g][r] = b_is[co] + b_ss[co];
        }
    }

    {
        bfrag_t z8 = {0,0,0,0,0,0,0,0};
        if (tid < 8)  *(bfrag_t*)&sX2[tid * 8] = z8;
        if (tid < 16) {
            *(bfrag_t*)&sH[tid * 8] = z8;
            *(bfrag_t*)&sH[65 * SHS + tid * 8] = z8;
        }
    }

    float creg[4] = {0.f, 0.f, 0.f, 0.f};
    const int wp  = wv * 16 + l15;

    const int xw  = tid & 63;
    const int xc2 = tid >> 6;
    float xr[16];
    #pragma unroll
    for (int e = 0; e < 16; ++e)
        xr[e] = x[((b * CIN + xc2 * 16 + e) * Hn + 0) * Wn + xw];
    {
        bfrag_t v0, v1;
        #pragma unroll
        for (int e = 0; e < 8; ++e) { v0[e] = f2bf(xr[e]); v1[e] = f2bf(xr[e + 8]); }
        *(bfrag_t*)&sX2[(xw + 1) * SXS2 + xc2 * 16]     = v0;
        *(bfrag_t*)&sX2[(xw + 1) * SXS2 + xc2 * 16 + 8] = v1;
        #pragma unroll
        for (int e = 0; e < 16; ++e)
            xr[e] = x[((b * CIN + xc2 * 16 + e) * Hn + 1) * Wn + xw];
    }

    const int cig = tid & 15;
    const int w0  = tid >> 4;
    const unsigned long long spinA = (unsigned long long)(flgA + (lane & 31));
    int fastok = l2m ? 1 : 0, failn = 0;

    __syncthreads();

    for (int h = 0; h < Hn; ++h) {
        const int    par = (h & 1) ^ 1;
        const short* rdA = hbufA + par * HBUF_SHORTS + b * Wn * HID;
        const short* rdB = hbufB + par * HBUF_SHORTS + b * Wn * HID;
        short*       wrA = hbufA + (h & 1) * HBUF_SHORTS + b * Wn * HID;
        short*       wrB = hbufB + (h & 1) * HBUF_SHORTS + b * Wn * HID;

        bfrag_t f0, f1, f2, f3;
        if (h > 0) {
            const unsigned tgt = (unsigned)h;
            bool fast = false;
            if (fastok) {                       // ---- L2 spin: sc0 loads, bounded ----
                int iters = 0;
                for (;;) {
                    unsigned f;
                    asm volatile("global_load_dword %0, %1, off sc0\n\t"
                                 "s_waitcnt vmcnt(0)"
                                 : "=v"(f) : "v"(spinA) : "memory");
                    if (__all((int)(f >= tgt))) { fast = true; break; }
                    if (++iters > POLL_TO) break;
                    __builtin_amdgcn_s_sleep(1);
                }
                if (!fast && ++failn >= 2) fastok = 0;
            }
            if (!fast) {                        // ---- LLC spin (R7 verbatim, always correct) ----
                for (;;) {
                    unsigned f = __hip_atomic_load(&flgB[lane & 31],
                                                   __ATOMIC_RELAXED, __HIP_MEMORY_SCOPE_AGENT);
                    if (__all((int)(f >= tgt))) break;
                    __builtin_amdgcn_s_sleep(1);
                }
            }
            asm volatile("" ::: "memory");

            if (fast) {                         // ---- h loads via local-XCD L2 ----
                const unsigned long long a0 = (unsigned long long)(rdA + (w0     ) * HID + cig * 8);
                const unsigned long long a1 = (unsigned long long)(rdA + (w0 + 16) * HID + cig * 8);
                const unsigned long long a2 = (unsigned long long)(rdA + (w0 + 32) * HID + cig * 8);
                const unsigned long long a3 = (unsigned long long)(rdA + (w0 + 48) * HID + cig * 8);
                asm volatile("global_load_dwordx4 %0, %4, off sc0\n\t"
                             "global_load_dwordx4 %1, %5, off sc0\n\t"
                             "global_load_dwordx4 %2, %6, off sc0\n\t"
                             "global_load_dwordx4 %3, %7, off sc0\n\t"
                             "s_waitcnt vmcnt(0)"
                             : "=&v"(f0), "=&v"(f1), "=&v"(f2), "=&v"(f3)
                             : "v"(a0), "v"(a1), "v"(a2), "v"(a3)
                             : "memory");
                __builtin_amdgcn_sched_barrier(0);
            } else {                            // ---- h loads via LLC (R7 verbatim) ----
                union { bfrag_t f; unsigned long long q[2]; } u0, u1, u2, u3;
                const unsigned long long* s0 = (const unsigned long long*)(rdB + (w0     ) * HID + cig * 8);
                const unsigned long long* s1 = (const unsigned long long*)(rdB + (w0 + 16) * HID + cig * 8);
                const unsigned long long* s2 = (const unsigned long long*)(rdB + (w0 + 32) * HID + cig * 8);
                const unsigned long long* s3 = (const unsigned long long*)(rdB + (w0 + 48) * HID + cig * 8);
                u0.q[0] = __hip_atomic_load(s0,     __ATOMIC_RELAXED, __HIP_MEMORY_SCOPE_AGENT);
                u0.q[1] = __hip_atomic_load(s0 + 1, __ATOMIC_RELAXED, __HIP_MEMORY_SCOPE_AGENT);
                u1.q[0] = __hip_atomic_load(s1,     __ATOMIC_RELAXED, __HIP_MEMORY_SCOPE_AGENT);
                u1.q[1] = __hip_atomic_load(s1 + 1, __ATOMIC_RELAXED, __HIP_MEMORY_SCOPE_AGENT);
                u2.q[0] = __hip_atomic_load(s2,     __ATOMIC_RELAXED, __HIP_MEMORY_SCOPE_AGENT);
                u2.q[1] = __hip_atomic_load(s2 + 1, __ATOMIC_RELAXED, __HIP_MEMORY_SCOPE_AGENT);
                u3.q[0] = __hip_atomic_load(s3,     __ATOMIC_RELAXED, __HIP_MEMORY_SCOPE_AGENT);
                u3.q[1] = __hip_atomic_load(s3 + 1, __ATOMIC_RELAXED, __HIP_MEMORY_SCOPE_AGENT);
                f0 = u0.f; f1 = u1.f; f2 = u2.f; f3 = u3.f;
            }
        } else {
            bfrag_t z8 = {0,0,0,0,0,0,0,0};
            f0 = z8; f1 = z8; f2 = z8; f3 = z8;
        }

        // ---- x-GEMM (kt 0..3) ----
        f4_t acc0 = {0.f,0.f,0.f,0.f}, acc1 = {0.f,0.f,0.f,0.f};
        f4_t acc2 = {0.f,0.f,0.f,0.f}, acc3 = {0.f,0.f,0.f,0.f};
        #pragma unroll
        for (int kt = 0; kt < 4; ++kt) {
            const short* src = &sX2[(wp + (kt >> 1)) * SXS2 + (kt & 1) * 32 + quad * 8];
            bfrag_t bf = *(const bfrag_t*)src;
            acc0 = __builtin_amdgcn_mfma_f32_16x16x32_bf16(a_frag[0][kt], bf, acc0, 0, 0, 0);
            acc1 = __builtin_amdgcn_mfma_f32_16x16x32_bf16(a_frag[1][kt], bf, acc1, 0, 0, 0);
            acc2 = __builtin_amdgcn_mfma_f32_16x16x32_bf16(a_frag[2][kt], bf, acc2, 0, 0, 0);
            acc3 = __builtin_amdgcn_mfma_f32_16x16x32_bf16(a_frag[3][kt], bf, acc3, 0, 0, 0);
        }

        // ---- h panel writes + S1 ----
        *(bfrag_t*)&sH[(w0 +  1) * SHS + cig * 8] = f0;
        *(bfrag_t*)&sH[(w0 + 17) * SHS + cig * 8] = f1;
        *(bfrag_t*)&sH[(w0 + 33) * SHS + cig * 8] = f2;
        *(bfrag_t*)&sH[(w0 + 49) * SHS + cig * 8] = f3;
        BAR_LGKM();

        // ---- h-GEMM (kt 4..15) ----
        #pragma unroll
        for (int kt = 4; kt < 16; ++kt) {
            const short* src = &sH[(wp + ((kt - 4) >> 2)) * SHS + ((kt - 4) & 3) * 32 + quad * 8];
            bfrag_t bf = *(const bfrag_t*)src;
            acc0 = __builtin_amdgcn_mfma_f32_16x16x32_bf16(a_frag[0][kt], bf, acc0, 0, 0, 0);
            acc1 = __builtin_amdgcn_mfma_f32_16x16x32_bf16(a_frag[1][kt], bf, acc1, 0, 0, 0);
            acc2 = __builtin_amdgcn_mfma_f32_16x16x32_bf16(a_frag[2][kt], bf, acc2, 0, 0, 0);
            acc3 = __builtin_amdgcn_mfma_f32_16x16x32_bf16(a_frag[3][kt], bf, acc3, 0, 0, 0);
        }

        // ---- phase C ----
        float hv[4];
        #pragma unroll
        for (int r = 0; r < 4; ++r) {
            float ig = sigm (acc0[r] + bias[0][r]);
            float fg = sigm (acc1[r] + bias[1][r]);
            float og = sigm (acc2[r] + bias[2][r]);
            float gg = tanhf_(acc3[r] + bias[3][r]);
            float c  = fg * creg[r] + ig * gg;
            creg[r]  = c;
            hv[r]    = og * tanhf_(c);
        }

        // ---- TAIL: publish h (L2 first, then LLC), per-wave flags after per-wave acks ----
        if (h + 1 < Hn) {
            unsigned p0 = (unsigned)(unsigned short)f2bf(hv[0]) |
                          ((unsigned)(unsigned short)f2bf(hv[1]) << 16);
            unsigned p1 = (unsigned)(unsigned short)f2bf(hv[2]) |
                          ((unsigned)(unsigned short)f2bf(hv[3]) << 16);
            unsigned long long pk = (unsigned long long)p0 | ((unsigned long long)p1 << 32);
            const int doff = wp * HID + jc * 16 + quad * 4;
            const unsigned nxt = (unsigned)(h + 1);
            if (l2m) {
                const unsigned long long aA = (unsigned long long)(wrA + doff);
                asm volatile("global_store_dwordx2 %0, %1, off" :: "v"(aA), "v"(pk) : "memory");
                asm volatile("s_waitcnt vmcnt(0)" ::: "memory");
                if (lane == 0) {
                    const unsigned long long fA = (unsigned long long)(flgA + jc * 4 + wv);
                    asm volatile("global_store_dword %0, %1, off" :: "v"(fA), "v"(nxt) : "memory");
                }
            }
            __hip_atomic_store((unsigned long long*)(wrB + doff), pk,
                               __ATOMIC_RELAXED, __HIP_MEMORY_SCOPE_AGENT);
            asm volatile("s_waitcnt vmcnt(0)" ::: "memory");
            if (lane == 0)
                __hip_atomic_store(&flgB[jc * 4 + wv], nxt,
                                   __ATOMIC_RELAXED, __HIP_MEMORY_SCOPE_AGENT);
        }

        __syncthreads();   // S2: LDS panels reusable

        // ---- off-chain tail: sX2(h+1), out-stores, x(h+2) prefetch ----
        if (h + 1 < Hn) {
            bfrag_t v0, v1;
            #pragma unroll
            for (int e = 0; e < 8; ++e) { v0[e] = f2bf(xr[e]); v1[e] = f2bf(xr[e + 8]); }
            *(bfrag_t*)&sX2[(xw + 1) * SXS2 + xc2 * 16]     = v0;
            *(bfrag_t*)&sX2[(xw + 1) * SXS2 + xc2 * 16 + 8] = v1;
        }

        #pragma unroll
        for (int r = 0; r < 4; ++r)
            out[((b * HID + jc * 16 + quad * 4 + r) * Hn + h) * Wn + wp] = hv[r];

        if (h + 2 < Hn) {
            #pragma unroll
            for (int e = 0; e < 16; ++e)
                xr[e] = x[((b * CIN + xc2 * 16 + e) * Hn + (h + 2)) * Wn + xw];
        }

        if (h + 1 < Hn)
            BAR_LGKM();   // S3: sX2(h+1) visible; VM ops stay in flight
    }
}

extern "C" void kernel_launch(void* const* d_in, const int* in_sizes, int n_in,
                              void* d_out, int out_size, void* d_ws, size_t ws_size,
                              hipStream_t stream) {
    const float* x    = (const float*)d_in[0];
    const float* w_is = (const float*)d_in[1];
    const float* b_is = (const float*)d_in[2];
    const float* w_ss = (const float*)d_in[3];
    const float* b_ss = (const float*)d_in[4];
    float* out = (float*)d_out;
    unsigned char* ws = (unsigned char*)d_ws;

    // zero flag lines + claim state only (h bufs gated by flags / h==0 fill)
    hipMemsetAsync(ws + FLG_OFF, 0, B_ * 256 + 1024, stream);

    // 256 blocks: 128 XCD-claimed worker roles + surplus exits. 1 block/CU, ~27KB LDS.
    rowlstm_kernel<<<dim3(NGRID), dim3(256), 0, stream>>>(x, w_is, b_is, w_ss, b_ss, out, ws);
}